// Round 5
// baseline (183.087 us; speedup 1.0000x reference)
//
#include <hip/hip_runtime.h>
#include <hip/hip_bf16.h>

#define B 128
#define N 1024
#define L 512
#define D 64

typedef float f32x4 __attribute__((ext_vector_type(4)));
typedef short bf16x8 __attribute__((ext_vector_type(8)));

// 8 fp32 -> 8 bf16 (RNE) via packed HW cvt
__device__ inline bf16x8 cvt8(float4 f0, float4 f1) {
    union { __hip_bfloat162 h2[4]; bf16x8 v; } u;
    u.h2[0] = __float22bfloat162_rn(make_float2(f0.x, f0.y));
    u.h2[1] = __float22bfloat162_rn(make_float2(f0.z, f0.w));
    u.h2[2] = __float22bfloat162_rn(make_float2(f1.x, f1.y));
    u.h2[3] = __float22bfloat162_rn(make_float2(f1.z, f1.w));
    return u.v;
}

// ws layout: float partials[3*B*4]   (one slot per block; = chunk_sum/ntok)
//
// grid = 3*B*4 blocks x 256 threads. Block (s,b,chunk): 256 tokens (64/wave as
// 4 MFMA token tiles) vs ALL regions of image Ib, B-fragments loaded straight
// from global (coalesced 16B/lane, L1/L2-resident) — no LDS staging, no
// main-loop barriers, no 64KB occupancy cap (fixes R4's 8.8% occupancy).
__global__ __launch_bounds__(256, 4) void sim_kernel(
        const float* __restrict__ T, const float* __restrict__ I,
        const float* __restrict__ tmask, const float* __restrict__ imask,
        const int* __restrict__ Iimp, const int* __restrict__ Simp,
        float* __restrict__ partials) {
    int blk = blockIdx.x;          // 0..1535
    int chunk = blk & 3;
    int bs = blk >> 2;             // 0..383
    int b = bs & (B - 1);
    int s = bs >> 7;
    int Tb = b, Ib = b;
    if (s == 1) Tb = Simp[b];
    else if (s == 2) Ib = Iimp[b];

    int tid = threadIdx.x;
    int w = tid >> 6;
    int lane = tid & 63;
    int q = lane >> 4;
    int c = lane & 15;

    __shared__ float red[12];      // [0..3]=ts [4..7]=is [8..11]=wsum

    // ---- mask sums -> counts (prefix masks) ----
    float ts = 0.f, is = 0.f;
    {
        const float* tm = tmask + (size_t)Tb * N;
        for (int i = tid; i < N; i += 256) ts += tm[i];
        const float* im = imask + (size_t)Ib * L;
        for (int i = tid; i < L; i += 256) is += im[i];
    }
    for (int off = 32; off > 0; off >>= 1) {
        ts += __shfl_down(ts, off);
        is += __shfl_down(is, off);
    }
    if (lane == 0) { red[w] = ts; red[4 + w] = is; }
    __syncthreads();
    int ntok = (int)(red[0] + red[1] + red[2] + red[3] + 0.5f);
    int nreg = (int)(red[4] + red[5] + red[6] + red[7] + 0.5f);

    int tok0 = chunk * 256;
    if (tok0 >= ntok) {            // masked chunk: emit zero partial, done
        if (tid == 0) partials[blk] = 0.f;
        return;
    }

    // ---- A fragments: 4 token tiles x 2 K-halves (rows < N always: safe) ----
    int wt0 = tok0 + w * 64;
    bf16x8 afrag[4][2];
#pragma unroll
    for (int tt = 0; tt < 4; ++tt) {
        const float* trow = T + ((size_t)Tb * N + wt0 + tt * 16 + c) * D;
#pragma unroll
        for (int h = 0; h < 2; ++h) {
            const float4* p = (const float4*)(trow + h * 32 + q * 8);
            afrag[tt][h] = cvt8(p[0], p[1]);
        }
    }

    float mx[4][4];
#pragma unroll
    for (int tt = 0; tt < 4; ++tt)
#pragma unroll
        for (int i = 0; i < 4; ++i) mx[tt][i] = -3.0e38f;

    // per-lane B pointer: region row (c) at k-offset q*8
    const float* Ip = I + (size_t)Ib * L * D + (size_t)c * D + q * 8;

    int full_rt = nreg >> 4;
    int rem = nreg & 15;

    // ---- full region tiles: coalesced global B loads + MFMA + fmax ----
#pragma unroll 1
    for (int rt = 0; rt < full_rt; ++rt) {
        const float4* p0 = (const float4*)(Ip + (size_t)rt * 16 * D);
        float4 f00 = p0[0], f01 = p0[1];        // h=0: k = q*8..+8
        float4 f10 = p0[8], f11 = p0[9];        // h=1: k = 32+q*8..+8
        bf16x8 b0 = cvt8(f00, f01);
        bf16x8 b1 = cvt8(f10, f11);
#pragma unroll
        for (int tt = 0; tt < 4; ++tt) {
            f32x4 acc = {0.f, 0.f, 0.f, 0.f};
            acc = __builtin_amdgcn_mfma_f32_16x16x32_bf16(afrag[tt][0], b0, acc, 0, 0, 0);
            acc = __builtin_amdgcn_mfma_f32_16x16x32_bf16(afrag[tt][1], b1, acc, 0, 0, 0);
#pragma unroll
            for (int i = 0; i < 4; ++i) mx[tt][i] = fmaxf(mx[tt][i], acc[i]);
        }
    }
    // ---- partial region tile (rows stay < L: nreg<=511 here => row<=511) ----
    if (rem) {
        const float4* p0 = (const float4*)(Ip + (size_t)full_rt * 16 * D);
        bf16x8 b0 = cvt8(p0[0], p0[1]);
        bf16x8 b1 = cvt8(p0[8], p0[9]);
        bool valid = c < rem;
#pragma unroll
        for (int tt = 0; tt < 4; ++tt) {
            f32x4 acc = {0.f, 0.f, 0.f, 0.f};
            acc = __builtin_amdgcn_mfma_f32_16x16x32_bf16(afrag[tt][0], b0, acc, 0, 0, 0);
            acc = __builtin_amdgcn_mfma_f32_16x16x32_bf16(afrag[tt][1], b1, acc, 0, 0, 0);
            if (valid) {
#pragma unroll
                for (int i = 0; i < 4; ++i) mx[tt][i] = fmaxf(mx[tt][i], acc[i]);
            }
        }
    }

    // ---- cross-lane max over the 16 cols (regions) ----
#pragma unroll
    for (int m = 1; m < 16; m <<= 1) {
#pragma unroll
        for (int tt = 0; tt < 4; ++tt)
#pragma unroll
            for (int i = 0; i < 4; ++i)
                mx[tt][i] = fmaxf(mx[tt][i], __shfl_xor(mx[tt][i], m));
    }

    // ---- masked token sum (C layout: row = q*4 + i within tile) ----
    float bsum = 0.f;
    if (c == 0) {
#pragma unroll
        for (int tt = 0; tt < 4; ++tt)
#pragma unroll
            for (int i = 0; i < 4; ++i) {
                int row = wt0 + tt * 16 + q * 4 + i;
                if (row < ntok) bsum += mx[tt][i];
            }
    }
    for (int off = 32; off > 0; off >>= 1) bsum += __shfl_down(bsum, off);
    if (lane == 0) red[8 + w] = bsum;
    __syncthreads();
    if (tid == 0)
        partials[blk] = (red[8] + red[9] + red[10] + red[11]) / (float)ntok;
}

// 1 block x 384 threads: fold 1536 partials -> 384 sims -> hinge -> loss
__global__ void loss_kernel(const float* __restrict__ partials,
                            float* __restrict__ out) {
    int tid = threadIdx.x;  // 0..383
    __shared__ float simsL[384];
    __shared__ float w6[6];
    const float4* p4 = (const float4*)partials;
    float4 v = p4[tid];
    simsL[tid] = v.x + v.y + v.z + v.w;
    __syncthreads();
    float per = 0.f;
    if (tid < B) {
        float anc  = simsL[tid];
        float simp = simsL[B + tid];
        float iimp = simsL[2 * B + tid];
        per = fmaxf(1.f + iimp - anc, 0.f) + fmaxf(1.f + simp - anc, 0.f);
    }
    for (int off = 32; off > 0; off >>= 1) per += __shfl_down(per, off);
    if ((tid & 63) == 0) w6[tid >> 6] = per;
    __syncthreads();
    if (tid == 0)
        out[0] = (w6[0] + w6[1] + w6[2] + w6[3] + w6[4] + w6[5]) / (float)B;
}

extern "C" void kernel_launch(void* const* d_in, const int* in_sizes, int n_in,
                              void* d_out, int out_size, void* d_ws, size_t ws_size,
                              hipStream_t stream) {
    const float* T     = (const float*)d_in[0];
    const float* I     = (const float*)d_in[1];
    const float* tmask = (const float*)d_in[2];
    const float* imask = (const float*)d_in[3];
    const int*   Iimp  = (const int*)d_in[4];
    const int*   Simp  = (const int*)d_in[5];
    float* partials = (float*)d_ws;   // 1536 floats

    sim_kernel<<<3 * B * 4, 256, 0, stream>>>(T, I, tmask, imask, Iimp, Simp, partials);
    loss_kernel<<<1, 384, 0, stream>>>(partials, (float*)d_out);
}

// Round 6
// 127.032 us; speedup vs baseline: 1.4413x; 1.4413x over previous
//
#include <hip/hip_runtime.h>
#include <hip/hip_bf16.h>

#define B 128
#define N 1024
#define L 512
#define D 64

typedef float f32x4 __attribute__((ext_vector_type(4)));
typedef short bf16x8 __attribute__((ext_vector_type(8)));

// 8 fp32 -> 8 bf16 (RNE) via packed HW cvt
__device__ inline bf16x8 cvt8(float4 f0, float4 f1) {
    union { __hip_bfloat162 h2[4]; bf16x8 v; } u;
    u.h2[0] = __float22bfloat162_rn(make_float2(f0.x, f0.y));
    u.h2[1] = __float22bfloat162_rn(make_float2(f0.z, f0.w));
    u.h2[2] = __float22bfloat162_rn(make_float2(f1.x, f1.y));
    u.h2[3] = __float22bfloat162_rn(make_float2(f1.z, f1.w));
    return u.v;
}

// ws: float partials[3*B*4]  (per-block chunk_sum/ntok)
//
// grid = 1536 blocks (s,b,token-chunk) x 256 thr. Double-buffered LDS staging
// of 64-region bf16 chunks in MFMA-fragment order (conflict-free ds_read_b128):
//   16B chunk ci = g*64+ln (g=rt*2+h): region rt*16+(ln&15), d = h*32+(ln>>4)*8
// Pipeline per iter: issue global loads k+1 -> compute k (LDS+MFMA) ->
// cvt+store k+1 -> barrier. One vmcnt latency exposure per block (chunk 0)
// instead of per-tile (R5's mistake: inline loads = 32 serial stalls/block).
__global__ __launch_bounds__(256, 4) void sim_kernel(
        const float* __restrict__ T, const float* __restrict__ I,
        const float* __restrict__ tmask, const float* __restrict__ imask,
        const int* __restrict__ Iimp, const int* __restrict__ Simp,
        float* __restrict__ partials) {
    int blk = blockIdx.x;          // 0..1535
    int chunk = blk & 3;
    int bs = blk >> 2;
    int b = bs & (B - 1);
    int s = bs >> 7;
    int Tb = b, Ib = b;
    if (s == 1) Tb = Simp[b];
    else if (s == 2) Ib = Iimp[b];

    int tid = threadIdx.x;
    int w = tid >> 6;
    int lane = tid & 63;
    int q = lane >> 4;
    int c = lane & 15;

    __shared__ unsigned short ldsI[2][64 * D];   // 2 x 8 KB bf16, fragment order
    __shared__ float red[12];                    // [0..3]=ts [4..7]=is [8..11]=wsum

    // ---- mask sums -> counts ----
    float ts = 0.f, is = 0.f;
    {
        const float* tm = tmask + (size_t)Tb * N;
        for (int i = tid; i < N; i += 256) ts += tm[i];
        const float* im = imask + (size_t)Ib * L;
        for (int i = tid; i < L; i += 256) is += im[i];
    }
    for (int off = 32; off > 0; off >>= 1) {
        ts += __shfl_down(ts, off);
        is += __shfl_down(is, off);
    }
    if (lane == 0) { red[w] = ts; red[4 + w] = is; }
    __syncthreads();
    int ntok = (int)(red[0] + red[1] + red[2] + red[3] + 0.5f);
    int nreg = (int)(red[4] + red[5] + red[6] + red[7] + 0.5f);

    int tok0 = chunk * 256;
    if (tok0 >= ntok) {
        if (tid == 0) partials[blk] = 0.f;
        return;
    }

    // ---- A fragments: 4 token tiles x 2 K-halves ----
    int wt0 = tok0 + w * 64;
    bf16x8 afrag[4][2];
#pragma unroll
    for (int tt = 0; tt < 4; ++tt) {
        const float* trow = T + ((size_t)Tb * N + wt0 + tt * 16 + c) * D;
#pragma unroll
        for (int h = 0; h < 2; ++h) {
            const float4* p = (const float4*)(trow + h * 32 + q * 8);
            afrag[tt][h] = cvt8(p[0], p[1]);
        }
    }

    float mx[4][4];
#pragma unroll
    for (int tt = 0; tt < 4; ++tt)
#pragma unroll
        for (int i = 0; i < 4; ++i) mx[tt][i] = -3.0e38f;

    // ---- staging thread map: two 16B bf16 chunks per thread ----
    int r_loc[2], db_loc[2];
#pragma unroll
    for (int j = 0; j < 2; ++j) {
        int ci = tid + j * 256;
        int g = ci >> 6, ln = ci & 63;
        r_loc[j] = (g >> 1) * 16 + (ln & 15);
        db_loc[j] = (g & 1) * 32 + (ln >> 4) * 8;
    }
    const float* Ibase = I + (size_t)Ib * L * D;
    int nchunks = (nreg + 63) >> 6;
    float4 pf[4];

    auto issue = [&](int k) {
        int rbase = k * 64;
#pragma unroll
        for (int j = 0; j < 2; ++j) {
            int r = rbase + r_loc[j];
            if (r < nreg) {
                const float4* p = (const float4*)(Ibase + (size_t)r * D + db_loc[j]);
                pf[2 * j] = p[0];
                pf[2 * j + 1] = p[1];
            } else {
                pf[2 * j] = make_float4(0.f, 0.f, 0.f, 0.f);
                pf[2 * j + 1] = make_float4(0.f, 0.f, 0.f, 0.f);
            }
        }
    };
    auto store = [&](int k) {
#pragma unroll
        for (int j = 0; j < 2; ++j) {
            int ci = tid + j * 256;
            *(bf16x8*)((char*)&ldsI[k & 1][0] + (size_t)ci * 16) = cvt8(pf[2 * j], pf[2 * j + 1]);
        }
    };

    issue(0);
    store(0);
    __syncthreads();

    for (int k = 0; k < nchunks; ++k) {
        if (k + 1 < nchunks) issue(k + 1);     // loads in flight over compute

        const char* base = (const char*)&ldsI[k & 1][0] + (size_t)lane * 16;
        int nvalid = nreg - k * 64;
        if (nvalid > 64) nvalid = 64;
        int nft = nvalid >> 4, prem = nvalid & 15;
        for (int rt = 0; rt < nft; ++rt) {
            bf16x8 b0 = *(const bf16x8*)(base + (size_t)(rt * 2 + 0) * 1024);
            bf16x8 b1 = *(const bf16x8*)(base + (size_t)(rt * 2 + 1) * 1024);
#pragma unroll
            for (int tt = 0; tt < 4; ++tt) {
                f32x4 acc = {0.f, 0.f, 0.f, 0.f};
                acc = __builtin_amdgcn_mfma_f32_16x16x32_bf16(afrag[tt][0], b0, acc, 0, 0, 0);
                acc = __builtin_amdgcn_mfma_f32_16x16x32_bf16(afrag[tt][1], b1, acc, 0, 0, 0);
#pragma unroll
                for (int i = 0; i < 4; ++i) mx[tt][i] = fmaxf(mx[tt][i], acc[i]);
            }
        }
        if (prem) {                             // boundary tile: predicated max
            bf16x8 b0 = *(const bf16x8*)(base + (size_t)(nft * 2 + 0) * 1024);
            bf16x8 b1 = *(const bf16x8*)(base + (size_t)(nft * 2 + 1) * 1024);
            bool valid = c < prem;
#pragma unroll
            for (int tt = 0; tt < 4; ++tt) {
                f32x4 acc = {0.f, 0.f, 0.f, 0.f};
                acc = __builtin_amdgcn_mfma_f32_16x16x32_bf16(afrag[tt][0], b0, acc, 0, 0, 0);
                acc = __builtin_amdgcn_mfma_f32_16x16x32_bf16(afrag[tt][1], b1, acc, 0, 0, 0);
                if (valid) {
#pragma unroll
                    for (int i = 0; i < 4; ++i) mx[tt][i] = fmaxf(mx[tt][i], acc[i]);
                }
            }
        }

        if (k + 1 < nchunks) {
            store(k + 1);                       // waits vmcnt here, post-compute
            __syncthreads();                    // one barrier per iteration
        }
    }

    // ---- cross-lane max over 16 region-cols ----
#pragma unroll
    for (int m = 1; m < 16; m <<= 1) {
#pragma unroll
        for (int tt = 0; tt < 4; ++tt)
#pragma unroll
            for (int i = 0; i < 4; ++i)
                mx[tt][i] = fmaxf(mx[tt][i], __shfl_xor(mx[tt][i], m));
    }

    // ---- masked token sum (C layout: row = q*4 + i) ----
    float bsum = 0.f;
    if (c == 0) {
#pragma unroll
        for (int tt = 0; tt < 4; ++tt)
#pragma unroll
            for (int i = 0; i < 4; ++i) {
                int row = wt0 + tt * 16 + q * 4 + i;
                if (row < ntok) bsum += mx[tt][i];
            }
    }
    for (int off = 32; off > 0; off >>= 1) bsum += __shfl_down(bsum, off);
    if (lane == 0) red[8 + w] = bsum;
    __syncthreads();
    if (tid == 0)
        partials[blk] = (red[8] + red[9] + red[10] + red[11]) / (float)ntok;
}

// 1 block x 384 threads: fold 1536 partials -> 384 sims -> hinge -> loss
__global__ void loss_kernel(const float* __restrict__ partials,
                            float* __restrict__ out) {
    int tid = threadIdx.x;  // 0..383
    __shared__ float simsL[384];
    __shared__ float w6[6];
    const float4* p4 = (const float4*)partials;
    float4 v = p4[tid];
    simsL[tid] = v.x + v.y + v.z + v.w;
    __syncthreads();
    float per = 0.f;
    if (tid < B) {
        float anc  = simsL[tid];
        float simp = simsL[B + tid];
        float iimp = simsL[2 * B + tid];
        per = fmaxf(1.f + iimp - anc, 0.f) + fmaxf(1.f + simp - anc, 0.f);
    }
    for (int off = 32; off > 0; off >>= 1) per += __shfl_down(per, off);
    if ((tid & 63) == 0) w6[tid >> 6] = per;
    __syncthreads();
    if (tid == 0)
        out[0] = (w6[0] + w6[1] + w6[2] + w6[3] + w6[4] + w6[5]) / (float)B;
}

extern "C" void kernel_launch(void* const* d_in, const int* in_sizes, int n_in,
                              void* d_out, int out_size, void* d_ws, size_t ws_size,
                              hipStream_t stream) {
    const float* T     = (const float*)d_in[0];
    const float* I     = (const float*)d_in[1];
    const float* tmask = (const float*)d_in[2];
    const float* imask = (const float*)d_in[3];
    const int*   Iimp  = (const int*)d_in[4];
    const int*   Simp  = (const int*)d_in[5];
    float* partials = (float*)d_ws;   // 1536 floats

    sim_kernel<<<3 * B * 4, 256, 0, stream>>>(T, I, tmask, imask, Iimp, Simp, partials);
    loss_kernel<<<1, 384, 0, stream>>>(partials, (float*)d_out);
}